// Round 11
// baseline (421.773 us; speedup 1.0000x reference)
//
#include <hip/hip_runtime.h>

#define NN 50000
#define NE 400000
#define NG 64
#define D 256
#define DOUT 16

typedef __attribute__((ext_vector_type(8))) short bf16x8;
typedef __attribute__((ext_vector_type(4))) float f32x4;

__device__ __forceinline__ short f2bf(float x) {
    union { float f; unsigned u; } v; v.f = x;
    unsigned r = v.u + 0x7fffu + ((v.u >> 16) & 1u);   // RNE
    return (short)(r >> 16);
}
__device__ __forceinline__ float bf2f(short h) {
    union { float f; unsigned u; } v;
    v.u = ((unsigned)(unsigned short)h) << 16;
    return v.f;
}

// async global->LDS 16B copy (dest = wave-uniform base + lane*16)
__device__ __forceinline__ void async_cp16(void* lds, const void* g) {
    __builtin_amdgcn_global_load_lds(
        (const __attribute__((address_space(1))) unsigned int*)g,
        (__attribute__((address_space(3))) unsigned int*)lds, 16, 0, 0);
}

// ---------------- init: zero cnt + zero pooled + per-graph inv counts ------

__global__ void k_init(int* __restrict__ cnt, float* __restrict__ pooled,
                       const int* __restrict__ batch, float* __restrict__ inv_cnt,
                       int n) {
    int i = blockIdx.x * 256 + threadIdx.x;
    if (i < n) cnt[i] = 0;
    if (i < NG * D) pooled[i] = 0.f;
    if (blockIdx.x == 0 && threadIdx.x < NG) {
        int g = threadIdx.x;
        int lo = 0, hi = n;
        while (lo < hi) { int mid = (lo + hi) >> 1; if (batch[mid] < g) lo = mid + 1; else hi = mid; }
        int start = lo;
        hi = n;
        while (lo < hi) { int mid = (lo + hi) >> 1; if (batch[mid] < g + 1) lo = mid + 1; else hi = mid; }
        inv_cnt[g] = 1.f / fmaxf((float)(lo - start), 1.f);
    }
}

__global__ void k_count(const int* __restrict__ eidx, int* __restrict__ cnt, int E) {
    int e = blockIdx.x * blockDim.x + threadIdx.x;
    if (e < E) atomicAdd(&cnt[eidx[E + e]], 1);
}

// exclusive scan of cnt[n] -> row_ptr[n] (+ dinv from final counts), 1024 elems/block
__global__ void k_scan1(const int* __restrict__ cnt, int* __restrict__ excl,
                        int* __restrict__ bsums, float* __restrict__ dinv, int n) {
    __shared__ int sh[256];
    int tid = threadIdx.x;
    int base = blockIdx.x * 1024;
    int v[4]; int tsum = 0;
    for (int j = 0; j < 4; ++j) {
        int i = base + tid * 4 + j;
        v[j] = (i < n) ? cnt[i] : 0;
        if (i < n) dinv[i] = rsqrtf((float)(v[j] + 1));  // +1 self-loop
        tsum += v[j];
    }
    sh[tid] = tsum; __syncthreads();
    for (int d = 1; d < 256; d <<= 1) {
        int t = (tid >= d) ? sh[tid - d] : 0;
        __syncthreads();
        sh[tid] += t;
        __syncthreads();
    }
    int run = sh[tid] - tsum;  // exclusive offset within block
    for (int j = 0; j < 4; ++j) {
        int i = base + tid * 4 + j;
        if (i < n) excl[i] = run;
        run += v[j];
    }
    if (tid == 255) bsums[blockIdx.x] = sh[255];
}

__global__ void k_scan2(int* bsums, int nb) {
    __shared__ int sh[64];
    int tid = threadIdx.x;
    int v = (tid < nb) ? bsums[tid] : 0;
    sh[tid] = v; __syncthreads();
    for (int d = 1; d < 64; d <<= 1) {
        int t = (tid >= d) ? sh[tid - d] : 0;
        __syncthreads();
        sh[tid] += t;
        __syncthreads();
    }
    if (tid < nb) bsums[tid] = sh[tid] - v;  // exclusive
}

__global__ void k_scan3(int* __restrict__ row_ptr, const int* __restrict__ bsums,
                        int* __restrict__ cursor, int n, int E) {
    int i = blockIdx.x * blockDim.x + threadIdx.x;
    if (i < n) {
        int v = row_ptr[i] + bsums[i >> 10];
        row_ptr[i] = v;
        cursor[i] = v;
    }
    if (i == 0) row_ptr[n] = E;
}

__global__ void k_fill(const int* __restrict__ eidx, int* __restrict__ cursor,
                       int* __restrict__ col_src, int E) {
    int e = blockIdx.x * blockDim.x + threadIdx.x;
    if (e < E) {
        int d = eidx[E + e];
        int pos = atomicAdd(&cursor[d], 1);
        col_src[pos] = eidx[e];
    }
}

// ---------------- split: x -> bf16 (hi only) + 3x W -> W^T hi/lo ----------

__global__ void k_split(const float* __restrict__ x, unsigned short* __restrict__ ahi,
                        int total4, int xblocks,
                        const float* __restrict__ W1, short* __restrict__ w1hi, short* __restrict__ w1lo,
                        const float* __restrict__ W2, short* __restrict__ w2hi, short* __restrict__ w2lo,
                        const float* __restrict__ W3, short* __restrict__ w3hi, short* __restrict__ w3lo) {
    if (blockIdx.x < (unsigned)xblocks) {
        int i = blockIdx.x * 256 + threadIdx.x;
        if (i >= total4) return;
        float4 v = ((const float4*)x)[i];
        ushort4 h;
        h.x = (unsigned short)f2bf(v.x);
        h.y = (unsigned short)f2bf(v.y);
        h.z = (unsigned short)f2bf(v.z);
        h.w = (unsigned short)f2bf(v.w);
        ((ushort4*)ahi)[i] = h;
    } else {
        int wb = blockIdx.x - xblocks;
        int which = wb >> 8;               // 0..2
        int idx = (wb & 255) * 256 + threadIdx.x;   // idx = n*256 + k
        int nn = idx >> 8, k = idx & 255;
        const float* W = (which == 0) ? W1 : (which == 1) ? W2 : W3;
        short* Whi = (which == 0) ? w1hi : (which == 1) ? w2hi : w3hi;
        short* Wlo = (which == 0) ? w1lo : (which == 1) ? w2lo : w3lo;
        float xv = W[k * 256 + nn];
        short h = f2bf(xv);
        Whi[idx] = h;
        Wlo[idx] = f2bf(xv - bf2f(h));
    }
}

// ---------------- MFMA GEMM: 64x256 tile, LDS-staged via global_load_lds ---
// A bf16 [M][256] (hi only); Wt hi/lo bf16 [256 n][256 k]. 4 waves, each owns
// 64 rows x 64 cols, BK=32. 782 blocks -> 3 blocks/CU (12 waves/CU), near-
// perfect grid balance. XOR swizzle q = c ^ ((r>>1)&3) folded into global
// source address. A*B ~= Ah*Bh + Ah*Bl.

__global__ __launch_bounds__(256, 3) void k_gemm_mfma(
        const unsigned short* __restrict__ A,
        const short* __restrict__ Whi, const short* __restrict__ Wlo,
        const float* __restrict__ dinv, unsigned short* __restrict__ C, int M) {
    __shared__ short Ah_s[2048];   //  4 KB: 64 rows x 32 k, swizzled
    __shared__ short Bh_s[8192];   // 16 KB: 256 rows x 32 k
    __shared__ short Bl_s[8192];   // 16 KB

    const int tid = threadIdx.x;
    const int bm = blockIdx.x * 64;

    const int lane = tid & 63;
    const int w    = tid >> 6;     // wave owns cols w*64 .. w*64+63
    const int lm   = lane & 15;
    const int quad = lane >> 4;

    // staging: thread covers row srow (0..63), 16B chunk c, swizzled quad q
    const int srow = tid >> 2, c = tid & 3;
    const int q = c ^ ((srow >> 1) & 3);
    int ga = bm + srow; if (ga >= M) ga = M - 1;     // clamp: dup rows never stored
    const unsigned short* pa = A + ((size_t)ga << 8) + q * 8;
    const short* pbh[4]; const short* pbl[4];
    #pragma unroll
    for (int j = 0; j < 4; ++j) {
        pbh[j] = Whi + ((size_t)(j * 64 + srow) << 8) + q * 8;
        pbl[j] = Wlo + ((size_t)(j * 64 + srow) << 8) + q * 8;
    }

    const int stA = w * 512;       // shorts; wave w stages A rows w*16..w*16+15
    int stB[4];
    #pragma unroll
    for (int j = 0; j < 4; ++j) stB[j] = j * 2048 + w * 512;

    // fragment LDS offsets (k0-invariant)
    int oa[4], ob[4];
    #pragma unroll
    for (int i = 0; i < 4; ++i) {
        int ra = i * 16 + lm;
        oa[i] = ra * 32 + ((quad ^ ((ra >> 1) & 3)) * 8);
        int rb = w * 64 + i * 16 + lm;
        ob[i] = rb * 32 + ((quad ^ ((rb >> 1) & 3)) * 8);
    }

    f32x4 acc[4][4];
    #pragma unroll
    for (int i = 0; i < 4; ++i)
        #pragma unroll
        for (int j = 0; j < 4; ++j)
            acc[i][j] = (f32x4){0.f, 0.f, 0.f, 0.f};

    for (int k0 = 0; k0 < D; k0 += 32) {
        async_cp16(&Ah_s[stA], pa + k0);
        #pragma unroll
        for (int j = 0; j < 4; ++j) {
            async_cp16(&Bh_s[stB[j]], pbh[j] + k0);
            async_cp16(&Bl_s[stB[j]], pbl[j] + k0);
        }
        __syncthreads();

        bf16x8 Ah[4], Bh[4], Bl[4];
        #pragma unroll
        for (int i = 0; i < 4; ++i) {
            Ah[i] = *(const bf16x8*)&Ah_s[oa[i]];
            Bh[i] = *(const bf16x8*)&Bh_s[ob[i]];
            Bl[i] = *(const bf16x8*)&Bl_s[ob[i]];
        }
        #pragma unroll
        for (int mi = 0; mi < 4; ++mi)
            #pragma unroll
            for (int ni = 0; ni < 4; ++ni) {
                acc[mi][ni] = __builtin_amdgcn_mfma_f32_16x16x32_bf16(Ah[mi], Bh[ni], acc[mi][ni], 0, 0, 0);
                acc[mi][ni] = __builtin_amdgcn_mfma_f32_16x16x32_bf16(Ah[mi], Bl[ni], acc[mi][ni], 0, 0, 0);
            }
        __syncthreads();
    }

    // epilogue: C[row][col] = bf16(acc * dinv[row])
    #pragma unroll
    for (int mi = 0; mi < 4; ++mi) {
        int rbase = bm + mi * 16 + quad * 4;
        #pragma unroll
        for (int r = 0; r < 4; ++r) {
            int grow = rbase + r;
            if (grow < M) {
                float s = dinv[grow];
                #pragma unroll
                for (int ni = 0; ni < 4; ++ni) {
                    int col = w * 64 + ni * 16 + lm;
                    C[(size_t)grow * D + col] = (unsigned short)f2bf(acc[mi][ni][r] * s);
                }
            }
        }
    }
}

// ---------------- agg core: accumulate h'[node] + sum h'[src] (2 nodes/wave) --

__device__ __forceinline__ void agg_two(
        const unsigned short* __restrict__ h, const int* __restrict__ row_ptr,
        const int* __restrict__ col_src, int n0, int n1, bool has1, int lane,
        float4& a0, float4& a1) {
    ushort4 s0 = ((const ushort4*)(h + (size_t)n0 * D))[lane];
    a0 = make_float4(bf2f(s0.x), bf2f(s0.y), bf2f(s0.z), bf2f(s0.w));
    a1 = make_float4(0.f, 0.f, 0.f, 0.f);
    if (has1) {
        ushort4 s1 = ((const ushort4*)(h + (size_t)n1 * D))[lane];
        a1 = make_float4(bf2f(s1.x), bf2f(s1.y), bf2f(s1.z), bf2f(s1.w));
    }
    int c0 = row_ptr[n0], e0 = row_ptr[n0 + 1];
    int c1 = e0, e1 = has1 ? row_ptr[n1 + 1] : e0;   // CSR-contiguous

    while (c0 < e0 || c1 < e1) {
        int cnt0 = min(64, e0 - c0); if (cnt0 < 0) cnt0 = 0;
        int cnt1 = min(64, e1 - c1); if (cnt1 < 0) cnt1 = 0;
        int i0 = (lane < cnt0) ? col_src[c0 + lane] : 0;
        int i1 = (lane < cnt1) ? col_src[c1 + lane] : 0;
        int m = max(cnt0, cnt1);
        for (int e = 0; e < m; e += 8) {
            int k0 = cnt0 - e;                        // wave-uniform
            int k1 = cnt1 - e;
            ushort4 u0[8], u1[8];
            #pragma unroll
            for (int j = 0; j < 8; ++j)
                if (j < k0) {
                    int s = __shfl(i0, e + j);
                    u0[j] = ((const ushort4*)(h + (size_t)s * D))[lane];
                }
            #pragma unroll
            for (int j = 0; j < 8; ++j)
                if (j < k1) {
                    int s = __shfl(i1, e + j);
                    u1[j] = ((const ushort4*)(h + (size_t)s * D))[lane];
                }
            #pragma unroll
            for (int j = 0; j < 8; ++j)
                if (j < k0) {
                    a0.x += bf2f(u0[j].x); a0.y += bf2f(u0[j].y);
                    a0.z += bf2f(u0[j].z); a0.w += bf2f(u0[j].w);
                }
            #pragma unroll
            for (int j = 0; j < 8; ++j)
                if (j < k1) {
                    a1.x += bf2f(u1[j].x); a1.y += bf2f(u1[j].y);
                    a1.z += bf2f(u1[j].z); a1.w += bf2f(u1[j].w);
                }
        }
        c0 += cnt0; c1 += cnt1;
    }
}

// all layers: out = relu(dinv*(acc) + b) written bf16 (next GEMM's A / pool src)
__global__ __launch_bounds__(256) void k_agg(
        const unsigned short* __restrict__ h, const float* __restrict__ dinv,
        const int* __restrict__ row_ptr, const int* __restrict__ col_src,
        const float* __restrict__ bias,
        unsigned short* __restrict__ ohi, int n) {
    int w = threadIdx.x >> 6, lane = threadIdx.x & 63;
    int n0 = blockIdx.x * 8 + w * 2;
    if (n0 >= n) return;
    int n1 = n0 + 1;
    bool has1 = n1 < n;
    float4 a0, a1;
    agg_two(h, row_ptr, col_src, n0, n1, has1, lane, a0, a1);

    float di0 = dinv[n0];
    float4 b = ((const float4*)bias)[lane];
    ushort4 o0;
    o0.x = (unsigned short)f2bf(fmaxf(a0.x * di0 + b.x, 0.f));
    o0.y = (unsigned short)f2bf(fmaxf(a0.y * di0 + b.y, 0.f));
    o0.z = (unsigned short)f2bf(fmaxf(a0.z * di0 + b.z, 0.f));
    o0.w = (unsigned short)f2bf(fmaxf(a0.w * di0 + b.w, 0.f));
    ((ushort4*)(ohi + (size_t)n0 * D))[lane] = o0;
    if (has1) {
        float di1 = dinv[n1];
        ushort4 o1;
        o1.x = (unsigned short)f2bf(fmaxf(a1.x * di1 + b.x, 0.f));
        o1.y = (unsigned short)f2bf(fmaxf(a1.y * di1 + b.y, 0.f));
        o1.z = (unsigned short)f2bf(fmaxf(a1.z * di1 + b.z, 0.f));
        o1.w = (unsigned short)f2bf(fmaxf(a1.w * di1 + b.w, 0.f));
        ((ushort4*)(ohi + (size_t)n1 * D))[lane] = o1;
    }
}

// ---------------- mean pool, stage 1: chunked sums + atomic flush ----------
// 64 contiguous nodes/block, register accumulate, atomics only at graph edges.

__global__ __launch_bounds__(256) void k_pool_sum(
        const unsigned short* __restrict__ hi,
        const int* __restrict__ batch, float* __restrict__ pooled, int n) {
    int beg = blockIdx.x * 64;
    if (beg >= n) return;
    int end = min(beg + 64, n);
    int t = threadIdx.x;  // dim t
    float acc = 0.f;
    int cur = batch[beg];
    for (int i = beg; i < end; ++i) {
        int g = batch[i];
        if (g != cur) {
            atomicAdd(&pooled[cur * D + t], acc);
            acc = 0.f;
            cur = g;
        }
        acc += bf2f(hi[(size_t)i * D + t]);
    }
    atomicAdd(&pooled[cur * D + t], acc);
}

// ---------------- final FC ----------------

__global__ void k_fc(const float* __restrict__ pooled, const float* __restrict__ inv_cnt,
                     const float* __restrict__ W, const float* __restrict__ b,
                     float* __restrict__ out) {
    int t = blockIdx.x * blockDim.x + threadIdx.x;
    if (t >= NG * DOUT) return;
    int g = t >> 4, o = t & 15;
    float acc = 0.f;
    for (int k = 0; k < D; ++k) acc += pooled[g * D + k] * W[k * DOUT + o];
    out[t] = acc * inv_cnt[g] + b[o];
}

// ---------------- launch ----------------

extern "C" void kernel_launch(void* const* d_in, const int* in_sizes, int n_in,
                              void* d_out, int out_size, void* d_ws, size_t ws_size,
                              hipStream_t stream) {
    const float* x    = (const float*)d_in[0];
    const int*   eidx = (const int*)d_in[1];
    const int*   batch= (const int*)d_in[2];
    const float* W1   = (const float*)d_in[3];
    const float* b1   = (const float*)d_in[4];
    const float* W2   = (const float*)d_in[5];
    const float* b2   = (const float*)d_in[6];
    const float* W3   = (const float*)d_in[7];
    const float* b3   = (const float*)d_in[8];
    const float* Wfc  = (const float*)d_in[9];
    const float* bfc  = (const float*)d_in[10];
    float* out = (float*)d_out;

    const int n = in_sizes[0] / D;      // 50000
    const int E = in_sizes[1] / 2;      // 400000

    // workspace layout (256B aligned slabs)
    char* p = (char*)d_ws;
    auto take = [&](size_t bytes) -> void* {
        void* q = (void*)p;
        p += (bytes + 255) & ~(size_t)255;
        return q;
    };
    int*   cnt     = (int*)take((size_t)n * 4);
    int*   row_ptr = (int*)take((size_t)(n + 1) * 4);
    int*   cursor  = (int*)take((size_t)n * 4);
    int*   col_src = (int*)take((size_t)E * 4);
    int*   bsums   = (int*)take(256 * 4);
    float* dinv    = (float*)take((size_t)n * 4);
    float* inv_cnt = (float*)take((size_t)NG * 4);
    short* w1hi    = (short*)take((size_t)D * D * 2);
    short* w1lo    = (short*)take((size_t)D * D * 2);
    short* w2hi    = (short*)take((size_t)D * D * 2);
    short* w2lo    = (short*)take((size_t)D * D * 2);
    short* w3hi    = (short*)take((size_t)D * D * 2);
    short* w3lo    = (short*)take((size_t)D * D * 2);
    unsigned short* hbuf = (unsigned short*)take((size_t)n * D * 2);  // bf16 h'
    unsigned short* ahi  = (unsigned short*)take((size_t)n * D * 2);  // bf16 A
    float* pooled  = (float*)take((size_t)NG * D * 4);

    int tb = 256;
    int gn = (n + tb - 1) / tb;
    int ge = (E + tb - 1) / tb;
    int nb = (n + 1023) / 1024;   // 49 scan blocks
    int total4 = n * D / 4;
    int xblocks = (total4 + 255) / 256;

    k_init<<<gn, tb, 0, stream>>>(cnt, pooled, batch, inv_cnt, n);
    k_split<<<xblocks + 3 * 256, tb, 0, stream>>>(x, ahi, total4, xblocks,
                                                  W1, w1hi, w1lo, W2, w2hi, w2lo, W3, w3hi, w3lo);
    k_count<<<ge, tb, 0, stream>>>(eidx, cnt, E);
    k_scan1<<<nb, 256, 0, stream>>>(cnt, row_ptr, bsums, dinv, n);
    k_scan2<<<1, 64, 0, stream>>>(bsums, nb);
    k_scan3<<<gn, tb, 0, stream>>>(row_ptr, bsums, cursor, n, E);
    k_fill<<<ge, tb, 0, stream>>>(eidx, cursor, col_src, E);

    int ggrid = (n + 63) / 64;
    int agrid = (n + 7) / 8;

    k_gemm_mfma<<<ggrid, 256, 0, stream>>>(ahi, w1hi, w1lo, dinv, hbuf, n);
    k_agg<<<agrid, 256, 0, stream>>>(hbuf, dinv, row_ptr, col_src, b1, ahi, n);

    k_gemm_mfma<<<ggrid, 256, 0, stream>>>(ahi, w2hi, w2lo, dinv, hbuf, n);
    k_agg<<<agrid, 256, 0, stream>>>(hbuf, dinv, row_ptr, col_src, b2, ahi, n);

    k_gemm_mfma<<<ggrid, 256, 0, stream>>>(ahi, w3hi, w3lo, dinv, hbuf, n);
    k_agg<<<agrid, 256, 0, stream>>>(hbuf, dinv, row_ptr, col_src, b3, ahi, n);

    k_pool_sum<<<(n + 63) / 64, 256, 0, stream>>>(ahi, batch, pooled, n);
    k_fc<<<4, 256, 0, stream>>>(pooled, inv_cnt, Wfc, bfc, out);
}

// Round 12
// 393.627 us; speedup vs baseline: 1.0715x; 1.0715x over previous
//
#include <hip/hip_runtime.h>

#define NN 50000
#define NE 400000
#define NG 64
#define D 256
#define DOUT 16

typedef __attribute__((ext_vector_type(8))) short bf16x8;
typedef __attribute__((ext_vector_type(4))) float f32x4;

__device__ __forceinline__ short f2bf(float x) {
    union { float f; unsigned u; } v; v.f = x;
    unsigned r = v.u + 0x7fffu + ((v.u >> 16) & 1u);   // RNE
    return (short)(r >> 16);
}
__device__ __forceinline__ float bf2f(short h) {
    union { float f; unsigned u; } v;
    v.u = ((unsigned)(unsigned short)h) << 16;
    return v.f;
}

// async global->LDS 16B copy (dest = wave-uniform base + lane*16)
__device__ __forceinline__ void async_cp16(void* lds, const void* g) {
    __builtin_amdgcn_global_load_lds(
        (const __attribute__((address_space(1))) unsigned int*)g,
        (__attribute__((address_space(3))) unsigned int*)lds, 16, 0, 0);
}

// ---------------- init: zero cnt + zero pooled + per-graph inv counts ------

__global__ void k_init(int* __restrict__ cnt, float* __restrict__ pooled,
                       const int* __restrict__ batch, float* __restrict__ inv_cnt,
                       int n) {
    int i = blockIdx.x * 256 + threadIdx.x;
    if (i < n) cnt[i] = 0;
    if (i < NG * D) pooled[i] = 0.f;
    if (blockIdx.x == 0 && threadIdx.x < NG) {
        int g = threadIdx.x;
        int lo = 0, hi = n;
        while (lo < hi) { int mid = (lo + hi) >> 1; if (batch[mid] < g) lo = mid + 1; else hi = mid; }
        int start = lo;
        hi = n;
        while (lo < hi) { int mid = (lo + hi) >> 1; if (batch[mid] < g + 1) lo = mid + 1; else hi = mid; }
        inv_cnt[g] = 1.f / fmaxf((float)(lo - start), 1.f);
    }
}

__global__ void k_count(const int* __restrict__ eidx, int* __restrict__ cnt, int E) {
    int e = blockIdx.x * blockDim.x + threadIdx.x;
    if (e < E) atomicAdd(&cnt[eidx[E + e]], 1);
}

// exclusive scan of cnt[n] -> row_ptr[n] (+ dinv from final counts), 1024 elems/block
__global__ void k_scan1(const int* __restrict__ cnt, int* __restrict__ excl,
                        int* __restrict__ bsums, float* __restrict__ dinv, int n) {
    __shared__ int sh[256];
    int tid = threadIdx.x;
    int base = blockIdx.x * 1024;
    int v[4]; int tsum = 0;
    for (int j = 0; j < 4; ++j) {
        int i = base + tid * 4 + j;
        v[j] = (i < n) ? cnt[i] : 0;
        if (i < n) dinv[i] = rsqrtf((float)(v[j] + 1));  // +1 self-loop
        tsum += v[j];
    }
    sh[tid] = tsum; __syncthreads();
    for (int d = 1; d < 256; d <<= 1) {
        int t = (tid >= d) ? sh[tid - d] : 0;
        __syncthreads();
        sh[tid] += t;
        __syncthreads();
    }
    int run = sh[tid] - tsum;  // exclusive offset within block
    for (int j = 0; j < 4; ++j) {
        int i = base + tid * 4 + j;
        if (i < n) excl[i] = run;
        run += v[j];
    }
    if (tid == 255) bsums[blockIdx.x] = sh[255];
}

__global__ void k_scan2(int* bsums, int nb) {
    __shared__ int sh[64];
    int tid = threadIdx.x;
    int v = (tid < nb) ? bsums[tid] : 0;
    sh[tid] = v; __syncthreads();
    for (int d = 1; d < 64; d <<= 1) {
        int t = (tid >= d) ? sh[tid - d] : 0;
        __syncthreads();
        sh[tid] += t;
        __syncthreads();
    }
    if (tid < nb) bsums[tid] = sh[tid] - v;  // exclusive
}

__global__ void k_scan3(int* __restrict__ row_ptr, const int* __restrict__ bsums,
                        int* __restrict__ cursor, int n, int E) {
    int i = blockIdx.x * blockDim.x + threadIdx.x;
    if (i < n) {
        int v = row_ptr[i] + bsums[i >> 10];
        row_ptr[i] = v;
        cursor[i] = v;
    }
    if (i == 0) row_ptr[n] = E;
}

__global__ void k_fill(const int* __restrict__ eidx, int* __restrict__ cursor,
                       int* __restrict__ col_src, int E) {
    int e = blockIdx.x * blockDim.x + threadIdx.x;
    if (e < E) {
        int d = eidx[E + e];
        int pos = atomicAdd(&cursor[d], 1);
        col_src[pos] = eidx[e];
    }
}

// ---------------- split: x -> bf16 (hi only) + 3x W -> W^T hi/lo ----------

__global__ void k_split(const float* __restrict__ x, unsigned short* __restrict__ ahi,
                        int total4, int xblocks,
                        const float* __restrict__ W1, short* __restrict__ w1hi, short* __restrict__ w1lo,
                        const float* __restrict__ W2, short* __restrict__ w2hi, short* __restrict__ w2lo,
                        const float* __restrict__ W3, short* __restrict__ w3hi, short* __restrict__ w3lo) {
    if (blockIdx.x < (unsigned)xblocks) {
        int i = blockIdx.x * 256 + threadIdx.x;
        if (i >= total4) return;
        float4 v = ((const float4*)x)[i];
        ushort4 h;
        h.x = (unsigned short)f2bf(v.x);
        h.y = (unsigned short)f2bf(v.y);
        h.z = (unsigned short)f2bf(v.z);
        h.w = (unsigned short)f2bf(v.w);
        ((ushort4*)ahi)[i] = h;
    } else {
        int wb = blockIdx.x - xblocks;
        int which = wb >> 8;               // 0..2
        int idx = (wb & 255) * 256 + threadIdx.x;   // idx = n*256 + k
        int nn = idx >> 8, k = idx & 255;
        const float* W = (which == 0) ? W1 : (which == 1) ? W2 : W3;
        short* Whi = (which == 0) ? w1hi : (which == 1) ? w2hi : w3hi;
        short* Wlo = (which == 0) ? w1lo : (which == 1) ? w2lo : w3lo;
        float xv = W[k * 256 + nn];
        short h = f2bf(xv);
        Whi[idx] = h;
        Wlo[idx] = f2bf(xv - bf2f(h));
    }
}

// ---------------- MFMA GEMM: 128x256 tile, BK=64, global_load_lds staging --
// A bf16 [M][256] (hi only); Wt hi/lo bf16 [256 n][256 k]. 4 waves of 64x128.
// BK=64 halves barrier count vs BK=32 (4 K-steps). LDS row = 64 shorts; slot
// (r, chunk c) holds k-chunk q = c ^ ((r>>1)&7), folded into global source
// address (32-row issues keep (r>>1)&7 issue-invariant). Second k-half frag
// offset = first ^ 32 shorts. 16-row ds_read_b128: 8 chunk values x 2 rows
// -> 32 banks, 2-way (free). A*B ~= Ah*Bh + Ah*Bl.

__global__ __launch_bounds__(256, 2) void k_gemm_mfma(
        const unsigned short* __restrict__ A,
        const short* __restrict__ Whi, const short* __restrict__ Wlo,
        const float* __restrict__ dinv, unsigned short* __restrict__ C, int M) {
    __shared__ short Ah_s[8192];    // 16 KB: 128 rows x 64 k, swizzled
    __shared__ short Bh_s[16384];   // 32 KB: 256 rows x 64 k
    __shared__ short Bl_s[16384];   // 32 KB

    const int tid = threadIdx.x;
    const int bm = blockIdx.x * 128;

    const int lane = tid & 63;
    const int w    = tid >> 6;
    const int wm   = w & 1;        // wave row half (0-1): 64 rows
    const int wn   = w >> 1;       // wave col half (0-1): 128 cols
    const int lm   = lane & 15;
    const int quad = lane >> 4;

    // staging: thread covers row srow (0..31 per 32-row issue), chunk c (0..7)
    const int srow = tid >> 3, c = tid & 7;
    const int q = c ^ ((srow >> 1) & 7);   // issue base (mult of 32) drops out
    const unsigned short* pa[4];
    #pragma unroll
    for (int j = 0; j < 4; ++j) {
        int ga = bm + j * 32 + srow; if (ga >= M) ga = M - 1;  // clamp: dups never stored
        pa[j] = A + ((size_t)ga << 8) + q * 8;
    }
    const short* pbh[8]; const short* pbl[8];
    #pragma unroll
    for (int j = 0; j < 8; ++j) {
        pbh[j] = Whi + ((size_t)(j * 32 + srow) << 8) + q * 8;
        pbl[j] = Wlo + ((size_t)(j * 32 + srow) << 8) + q * 8;
    }

    // wave-uniform LDS dest bases (shorts): issue j at j*2048, wave w at +w*512
    int st[8];
    #pragma unroll
    for (int j = 0; j < 8; ++j) st[j] = j * 2048 + w * 512;

    // fragment LDS offsets for k-half 0 (k-half 1 = offset ^ 32)
    int oa[4], ob[8];
    #pragma unroll
    for (int i = 0; i < 4; ++i) {
        int ra = wm * 64 + i * 16 + lm;
        oa[i] = ra * 64 + ((quad ^ ((ra >> 1) & 7)) * 8);
    }
    #pragma unroll
    for (int i = 0; i < 8; ++i) {
        int rb = wn * 128 + i * 16 + lm;
        ob[i] = rb * 64 + ((quad ^ ((rb >> 1) & 7)) * 8);
    }

    f32x4 acc[4][8];
    #pragma unroll
    for (int i = 0; i < 4; ++i)
        #pragma unroll
        for (int j = 0; j < 8; ++j)
            acc[i][j] = (f32x4){0.f, 0.f, 0.f, 0.f};

    for (int k0 = 0; k0 < D; k0 += 64) {
        #pragma unroll
        for (int j = 0; j < 4; ++j) async_cp16(&Ah_s[st[j]], pa[j] + k0);
        #pragma unroll
        for (int j = 0; j < 8; ++j) {
            async_cp16(&Bh_s[st[j]], pbh[j] + k0);
            async_cp16(&Bl_s[st[j]], pbl[j] + k0);
        }
        __syncthreads();

        #pragma unroll
        for (int kh = 0; kh < 2; ++kh) {
            const int xo = kh * 32;
            bf16x8 Ah[4], Bh[8], Bl[8];
            #pragma unroll
            for (int i = 0; i < 4; ++i) Ah[i] = *(const bf16x8*)&Ah_s[oa[i] ^ xo];
            #pragma unroll
            for (int i = 0; i < 8; ++i) {
                Bh[i] = *(const bf16x8*)&Bh_s[ob[i] ^ xo];
                Bl[i] = *(const bf16x8*)&Bl_s[ob[i] ^ xo];
            }
            #pragma unroll
            for (int mi = 0; mi < 4; ++mi)
                #pragma unroll
                for (int ni = 0; ni < 8; ++ni) {
                    acc[mi][ni] = __builtin_amdgcn_mfma_f32_16x16x32_bf16(Ah[mi], Bh[ni], acc[mi][ni], 0, 0, 0);
                    acc[mi][ni] = __builtin_amdgcn_mfma_f32_16x16x32_bf16(Ah[mi], Bl[ni], acc[mi][ni], 0, 0, 0);
                }
        }
        __syncthreads();
    }

    // epilogue: C[row][col] = bf16(acc * dinv[row])
    #pragma unroll
    for (int mi = 0; mi < 4; ++mi) {
        int rbase = bm + wm * 64 + mi * 16 + quad * 4;
        #pragma unroll
        for (int r = 0; r < 4; ++r) {
            int grow = rbase + r;
            if (grow < M) {
                float s = dinv[grow];
                #pragma unroll
                for (int ni = 0; ni < 8; ++ni) {
                    int col = wn * 128 + ni * 16 + lm;
                    C[(size_t)grow * D + col] = (unsigned short)f2bf(acc[mi][ni][r] * s);
                }
            }
        }
    }
}

// ---------------- agg core: accumulate h'[node] + sum h'[src] (2 nodes/wave) --

__device__ __forceinline__ void agg_two(
        const unsigned short* __restrict__ h, const int* __restrict__ row_ptr,
        const int* __restrict__ col_src, int n0, int n1, bool has1, int lane,
        float4& a0, float4& a1) {
    ushort4 s0 = ((const ushort4*)(h + (size_t)n0 * D))[lane];
    a0 = make_float4(bf2f(s0.x), bf2f(s0.y), bf2f(s0.z), bf2f(s0.w));
    a1 = make_float4(0.f, 0.f, 0.f, 0.f);
    if (has1) {
        ushort4 s1 = ((const ushort4*)(h + (size_t)n1 * D))[lane];
        a1 = make_float4(bf2f(s1.x), bf2f(s1.y), bf2f(s1.z), bf2f(s1.w));
    }
    int c0 = row_ptr[n0], e0 = row_ptr[n0 + 1];
    int c1 = e0, e1 = has1 ? row_ptr[n1 + 1] : e0;   // CSR-contiguous

    while (c0 < e0 || c1 < e1) {
        int cnt0 = min(64, e0 - c0); if (cnt0 < 0) cnt0 = 0;
        int cnt1 = min(64, e1 - c1); if (cnt1 < 0) cnt1 = 0;
        int i0 = (lane < cnt0) ? col_src[c0 + lane] : 0;
        int i1 = (lane < cnt1) ? col_src[c1 + lane] : 0;
        int m = max(cnt0, cnt1);
        for (int e = 0; e < m; e += 8) {
            int k0 = cnt0 - e;                        // wave-uniform
            int k1 = cnt1 - e;
            ushort4 u0[8], u1[8];
            #pragma unroll
            for (int j = 0; j < 8; ++j)
                if (j < k0) {
                    int s = __shfl(i0, e + j);
                    u0[j] = ((const ushort4*)(h + (size_t)s * D))[lane];
                }
            #pragma unroll
            for (int j = 0; j < 8; ++j)
                if (j < k1) {
                    int s = __shfl(i1, e + j);
                    u1[j] = ((const ushort4*)(h + (size_t)s * D))[lane];
                }
            #pragma unroll
            for (int j = 0; j < 8; ++j)
                if (j < k0) {
                    a0.x += bf2f(u0[j].x); a0.y += bf2f(u0[j].y);
                    a0.z += bf2f(u0[j].z); a0.w += bf2f(u0[j].w);
                }
            #pragma unroll
            for (int j = 0; j < 8; ++j)
                if (j < k1) {
                    a1.x += bf2f(u1[j].x); a1.y += bf2f(u1[j].y);
                    a1.z += bf2f(u1[j].z); a1.w += bf2f(u1[j].w);
                }
        }
        c0 += cnt0; c1 += cnt1;
    }
}

// all layers: out = relu(dinv*(acc) + b) written bf16 (next GEMM's A / pool src)
__global__ __launch_bounds__(256) void k_agg(
        const unsigned short* __restrict__ h, const float* __restrict__ dinv,
        const int* __restrict__ row_ptr, const int* __restrict__ col_src,
        const float* __restrict__ bias,
        unsigned short* __restrict__ ohi, int n) {
    int w = threadIdx.x >> 6, lane = threadIdx.x & 63;
    int n0 = blockIdx.x * 8 + w * 2;
    if (n0 >= n) return;
    int n1 = n0 + 1;
    bool has1 = n1 < n;
    float4 a0, a1;
    agg_two(h, row_ptr, col_src, n0, n1, has1, lane, a0, a1);

    float di0 = dinv[n0];
    float4 b = ((const float4*)bias)[lane];
    ushort4 o0;
    o0.x = (unsigned short)f2bf(fmaxf(a0.x * di0 + b.x, 0.f));
    o0.y = (unsigned short)f2bf(fmaxf(a0.y * di0 + b.y, 0.f));
    o0.z = (unsigned short)f2bf(fmaxf(a0.z * di0 + b.z, 0.f));
    o0.w = (unsigned short)f2bf(fmaxf(a0.w * di0 + b.w, 0.f));
    ((ushort4*)(ohi + (size_t)n0 * D))[lane] = o0;
    if (has1) {
        float di1 = dinv[n1];
        ushort4 o1;
        o1.x = (unsigned short)f2bf(fmaxf(a1.x * di1 + b.x, 0.f));
        o1.y = (unsigned short)f2bf(fmaxf(a1.y * di1 + b.y, 0.f));
        o1.z = (unsigned short)f2bf(fmaxf(a1.z * di1 + b.z, 0.f));
        o1.w = (unsigned short)f2bf(fmaxf(a1.w * di1 + b.w, 0.f));
        ((ushort4*)(ohi + (size_t)n1 * D))[lane] = o1;
    }
}

// ---------------- mean pool, stage 1: chunked sums + atomic flush ----------
// 64 contiguous nodes/block, register accumulate, atomics only at graph edges.

__global__ __launch_bounds__(256) void k_pool_sum(
        const unsigned short* __restrict__ hi,
        const int* __restrict__ batch, float* __restrict__ pooled, int n) {
    int beg = blockIdx.x * 64;
    if (beg >= n) return;
    int end = min(beg + 64, n);
    int t = threadIdx.x;  // dim t
    float acc = 0.f;
    int cur = batch[beg];
    for (int i = beg; i < end; ++i) {
        int g = batch[i];
        if (g != cur) {
            atomicAdd(&pooled[cur * D + t], acc);
            acc = 0.f;
            cur = g;
        }
        acc += bf2f(hi[(size_t)i * D + t]);
    }
    atomicAdd(&pooled[cur * D + t], acc);
}

// ---------------- final FC ----------------

__global__ void k_fc(const float* __restrict__ pooled, const float* __restrict__ inv_cnt,
                     const float* __restrict__ W, const float* __restrict__ b,
                     float* __restrict__ out) {
    int t = blockIdx.x * blockDim.x + threadIdx.x;
    if (t >= NG * DOUT) return;
    int g = t >> 4, o = t & 15;
    float acc = 0.f;
    for (int k = 0; k < D; ++k) acc += pooled[g * D + k] * W[k * DOUT + o];
    out[t] = acc * inv_cnt[g] + b[o];
}

// ---------------- launch ----------------

extern "C" void kernel_launch(void* const* d_in, const int* in_sizes, int n_in,
                              void* d_out, int out_size, void* d_ws, size_t ws_size,
                              hipStream_t stream) {
    const float* x    = (const float*)d_in[0];
    const int*   eidx = (const int*)d_in[1];
    const int*   batch= (const int*)d_in[2];
    const float* W1   = (const float*)d_in[3];
    const float* b1   = (const float*)d_in[4];
    const float* W2   = (const float*)d_in[5];
    const float* b2   = (const float*)d_in[6];
    const float* W3   = (const float*)d_in[7];
    const float* b3   = (const float*)d_in[8];
    const float* Wfc  = (const float*)d_in[9];
    const float* bfc  = (const float*)d_in[10];
    float* out = (float*)d_out;

    const int n = in_sizes[0] / D;      // 50000
    const int E = in_sizes[1] / 2;      // 400000

    // workspace layout (256B aligned slabs)
    char* p = (char*)d_ws;
    auto take = [&](size_t bytes) -> void* {
        void* q = (void*)p;
        p += (bytes + 255) & ~(size_t)255;
        return q;
    };
    int*   cnt     = (int*)take((size_t)n * 4);
    int*   row_ptr = (int*)take((size_t)(n + 1) * 4);
    int*   cursor  = (int*)take((size_t)n * 4);
    int*   col_src = (int*)take((size_t)E * 4);
    int*   bsums   = (int*)take(256 * 4);
    float* dinv    = (float*)take((size_t)n * 4);
    float* inv_cnt = (float*)take((size_t)NG * 4);
    short* w1hi    = (short*)take((size_t)D * D * 2);
    short* w1lo    = (short*)take((size_t)D * D * 2);
    short* w2hi    = (short*)take((size_t)D * D * 2);
    short* w2lo    = (short*)take((size_t)D * D * 2);
    short* w3hi    = (short*)take((size_t)D * D * 2);
    short* w3lo    = (short*)take((size_t)D * D * 2);
    unsigned short* hbuf = (unsigned short*)take((size_t)n * D * 2);  // bf16 h'
    unsigned short* ahi  = (unsigned short*)take((size_t)n * D * 2);  // bf16 A
    float* pooled  = (float*)take((size_t)NG * D * 4);

    int tb = 256;
    int gn = (n + tb - 1) / tb;
    int ge = (E + tb - 1) / tb;
    int nb = (n + 1023) / 1024;   // 49 scan blocks
    int total4 = n * D / 4;
    int xblocks = (total4 + 255) / 256;

    k_init<<<gn, tb, 0, stream>>>(cnt, pooled, batch, inv_cnt, n);
    k_split<<<xblocks + 3 * 256, tb, 0, stream>>>(x, ahi, total4, xblocks,
                                                  W1, w1hi, w1lo, W2, w2hi, w2lo, W3, w3hi, w3lo);
    k_count<<<ge, tb, 0, stream>>>(eidx, cnt, E);
    k_scan1<<<nb, 256, 0, stream>>>(cnt, row_ptr, bsums, dinv, n);
    k_scan2<<<1, 64, 0, stream>>>(bsums, nb);
    k_scan3<<<gn, tb, 0, stream>>>(row_ptr, bsums, cursor, n, E);
    k_fill<<<ge, tb, 0, stream>>>(eidx, cursor, col_src, E);

    int ggrid = (n + 127) / 128;
    int agrid = (n + 7) / 8;

    k_gemm_mfma<<<ggrid, 256, 0, stream>>>(ahi, w1hi, w1lo, dinv, hbuf, n);
    k_agg<<<agrid, 256, 0, stream>>>(hbuf, dinv, row_ptr, col_src, b1, ahi, n);

    k_gemm_mfma<<<ggrid, 256, 0, stream>>>(ahi, w2hi, w2lo, dinv, hbuf, n);
    k_agg<<<agrid, 256, 0, stream>>>(hbuf, dinv, row_ptr, col_src, b2, ahi, n);

    k_gemm_mfma<<<ggrid, 256, 0, stream>>>(ahi, w3hi, w3lo, dinv, hbuf, n);
    k_agg<<<agrid, 256, 0, stream>>>(hbuf, dinv, row_ptr, col_src, b3, ahi, n);

    k_pool_sum<<<(n + 63) / 64, 256, 0, stream>>>(ahi, batch, pooled, n);
    k_fc<<<4, 256, 0, stream>>>(pooled, inv_cnt, Wfc, bfc, out);
}

// Round 13
// 367.755 us; speedup vs baseline: 1.1469x; 1.0703x over previous
//
#include <hip/hip_runtime.h>

#define NN 50000
#define NE 400000
#define NG 64
#define D 256
#define DOUT 16

typedef __attribute__((ext_vector_type(8))) short bf16x8;
typedef __attribute__((ext_vector_type(8))) unsigned short u16x8;
typedef __attribute__((ext_vector_type(4))) float f32x4;

__device__ __forceinline__ short f2bf(float x) {
    union { float f; unsigned u; } v; v.f = x;
    unsigned r = v.u + 0x7fffu + ((v.u >> 16) & 1u);   // RNE
    return (short)(r >> 16);
}
__device__ __forceinline__ float bf2f(short h) {
    union { float f; unsigned u; } v;
    v.u = ((unsigned)(unsigned short)h) << 16;
    return v.f;
}

// async global->LDS 16B copy (dest = wave-uniform base + lane*16)
__device__ __forceinline__ void async_cp16(void* lds, const void* g) {
    __builtin_amdgcn_global_load_lds(
        (const __attribute__((address_space(1))) unsigned int*)g,
        (__attribute__((address_space(3))) unsigned int*)lds, 16, 0, 0);
}

// ---------------- init: zero cnt + zero pooled + per-graph inv counts ------

__global__ void k_init(int* __restrict__ cnt, float* __restrict__ pooled,
                       const int* __restrict__ batch, float* __restrict__ inv_cnt,
                       int n) {
    int i = blockIdx.x * 256 + threadIdx.x;
    if (i < n) cnt[i] = 0;
    if (i < NG * D) pooled[i] = 0.f;
    if (blockIdx.x == 0 && threadIdx.x < NG) {
        int g = threadIdx.x;
        int lo = 0, hi = n;
        while (lo < hi) { int mid = (lo + hi) >> 1; if (batch[mid] < g) lo = mid + 1; else hi = mid; }
        int start = lo;
        hi = n;
        while (lo < hi) { int mid = (lo + hi) >> 1; if (batch[mid] < g + 1) lo = mid + 1; else hi = mid; }
        inv_cnt[g] = 1.f / fmaxf((float)(lo - start), 1.f);
    }
}

// ---------------- fused: x->bf16 + 3x W^T hi/lo split + edge count ---------
// grid = xblocks + 768 + eblocks

__global__ void k_split_count(const float* __restrict__ x, unsigned short* __restrict__ ahi,
                              int total4, int xblocks,
                              const float* __restrict__ W1, short* __restrict__ w1hi, short* __restrict__ w1lo,
                              const float* __restrict__ W2, short* __restrict__ w2hi, short* __restrict__ w2lo,
                              const float* __restrict__ W3, short* __restrict__ w3hi, short* __restrict__ w3lo,
                              const int* __restrict__ eidx, int* __restrict__ cnt, int E) {
    int b = blockIdx.x;
    if (b < xblocks) {
        int i = b * 256 + threadIdx.x;
        if (i >= total4) return;
        float4 v = ((const float4*)x)[i];
        ushort4 h;
        h.x = (unsigned short)f2bf(v.x);
        h.y = (unsigned short)f2bf(v.y);
        h.z = (unsigned short)f2bf(v.z);
        h.w = (unsigned short)f2bf(v.w);
        ((ushort4*)ahi)[i] = h;
    } else if (b < xblocks + 3 * 256) {
        int wb = b - xblocks;
        int which = wb >> 8;               // 0..2
        int idx = (wb & 255) * 256 + threadIdx.x;   // idx = n*256 + k
        int nn = idx >> 8, k = idx & 255;
        const float* W = (which == 0) ? W1 : (which == 1) ? W2 : W3;
        short* Whi = (which == 0) ? w1hi : (which == 1) ? w2hi : w3hi;
        short* Wlo = (which == 0) ? w1lo : (which == 1) ? w2lo : w3lo;
        float xv = W[k * 256 + nn];
        short h = f2bf(xv);
        Whi[idx] = h;
        Wlo[idx] = f2bf(xv - bf2f(h));
    } else {
        int e = (b - xblocks - 3 * 256) * 256 + threadIdx.x;
        if (e < E) atomicAdd(&cnt[eidx[E + e]], 1);
    }
}

// exclusive scan of cnt[n] -> excl[n] (+ dinv from final counts), 1024 elems/block
__global__ void k_scan1(const int* __restrict__ cnt, int* __restrict__ excl,
                        int* __restrict__ bsums, float* __restrict__ dinv, int n) {
    __shared__ int sh[256];
    int tid = threadIdx.x;
    int base = blockIdx.x * 1024;
    int v[4]; int tsum = 0;
    for (int j = 0; j < 4; ++j) {
        int i = base + tid * 4 + j;
        v[j] = (i < n) ? cnt[i] : 0;
        if (i < n) dinv[i] = rsqrtf((float)(v[j] + 1));  // +1 self-loop
        tsum += v[j];
    }
    sh[tid] = tsum; __syncthreads();
    for (int d = 1; d < 256; d <<= 1) {
        int t = (tid >= d) ? sh[tid - d] : 0;
        __syncthreads();
        sh[tid] += t;
        __syncthreads();
    }
    int run = sh[tid] - tsum;  // exclusive offset within block
    for (int j = 0; j < 4; ++j) {
        int i = base + tid * 4 + j;
        if (i < n) excl[i] = run;
        run += v[j];
    }
    if (tid == 255) bsums[blockIdx.x] = sh[255];
}

// add bsums-prefix (computed in-wave per block) -> row_ptr, cursor
__global__ void k_scan3(int* __restrict__ row_ptr, const int* __restrict__ bsums,
                        int* __restrict__ cursor, int n, int E, int nb) {
    __shared__ int off_s;
    int chunk = (int)(blockIdx.x >> 2);   // block covers 256 idxs, 4 blocks per 1024-chunk
    if (threadIdx.x < 64) {
        int v = ((int)threadIdx.x < nb && (int)threadIdx.x < chunk) ? bsums[threadIdx.x] : 0;
        #pragma unroll
        for (int d = 1; d < 64; d <<= 1) v += __shfl_xor(v, d);
        if (threadIdx.x == 0) off_s = v;
    }
    __syncthreads();
    int off = off_s;
    int i = blockIdx.x * 256 + threadIdx.x;
    if (i < n) {
        int v = row_ptr[i] + off;
        row_ptr[i] = v;
        cursor[i] = v;
    }
    if (i == 0) row_ptr[n] = E;
}

__global__ void k_fill(const int* __restrict__ eidx, int* __restrict__ cursor,
                       int* __restrict__ col_src, int E) {
    int e = blockIdx.x * blockDim.x + threadIdx.x;
    if (e < E) {
        int d = eidx[E + e];
        int pos = atomicAdd(&cursor[d], 1);
        col_src[pos] = eidx[e];
    }
}

// ---------------- MFMA GEMM: 128x256 tile, BK=64, global_load_lds staging --
// A bf16 [M][256] (hi only); Wt hi/lo bf16 [256 n][256 k]. 4 waves of 64x128.
// LDS row = 64 shorts; slot (r, chunk c) holds k-chunk q = c ^ ((r>>1)&7),
// folded into global source address. Second k-half frag offset = first ^ 32.
// A*B ~= Ah*Bh + Ah*Bl.

__global__ __launch_bounds__(256, 2) void k_gemm_mfma(
        const unsigned short* __restrict__ A,
        const short* __restrict__ Whi, const short* __restrict__ Wlo,
        const float* __restrict__ dinv, unsigned short* __restrict__ C, int M) {
    __shared__ short Ah_s[8192];    // 16 KB: 128 rows x 64 k, swizzled
    __shared__ short Bh_s[16384];   // 32 KB: 256 rows x 64 k
    __shared__ short Bl_s[16384];   // 32 KB

    const int tid = threadIdx.x;
    const int bm = blockIdx.x * 128;

    const int lane = tid & 63;
    const int w    = tid >> 6;
    const int wm   = w & 1;        // wave row half (0-1): 64 rows
    const int wn   = w >> 1;       // wave col half (0-1): 128 cols
    const int lm   = lane & 15;
    const int quad = lane >> 4;

    const int srow = tid >> 3, c = tid & 7;
    const int q = c ^ ((srow >> 1) & 7);
    const unsigned short* pa[4];
    #pragma unroll
    for (int j = 0; j < 4; ++j) {
        int ga = bm + j * 32 + srow; if (ga >= M) ga = M - 1;
        pa[j] = A + ((size_t)ga << 8) + q * 8;
    }
    const short* pbh[8]; const short* pbl[8];
    #pragma unroll
    for (int j = 0; j < 8; ++j) {
        pbh[j] = Whi + ((size_t)(j * 32 + srow) << 8) + q * 8;
        pbl[j] = Wlo + ((size_t)(j * 32 + srow) << 8) + q * 8;
    }

    int st[8];
    #pragma unroll
    for (int j = 0; j < 8; ++j) st[j] = j * 2048 + w * 512;

    int oa[4], ob[8];
    #pragma unroll
    for (int i = 0; i < 4; ++i) {
        int ra = wm * 64 + i * 16 + lm;
        oa[i] = ra * 64 + ((quad ^ ((ra >> 1) & 7)) * 8);
    }
    #pragma unroll
    for (int i = 0; i < 8; ++i) {
        int rb = wn * 128 + i * 16 + lm;
        ob[i] = rb * 64 + ((quad ^ ((rb >> 1) & 7)) * 8);
    }

    f32x4 acc[4][8];
    #pragma unroll
    for (int i = 0; i < 4; ++i)
        #pragma unroll
        for (int j = 0; j < 8; ++j)
            acc[i][j] = (f32x4){0.f, 0.f, 0.f, 0.f};

    for (int k0 = 0; k0 < D; k0 += 64) {
        #pragma unroll
        for (int j = 0; j < 4; ++j) async_cp16(&Ah_s[st[j]], pa[j] + k0);
        #pragma unroll
        for (int j = 0; j < 8; ++j) {
            async_cp16(&Bh_s[st[j]], pbh[j] + k0);
            async_cp16(&Bl_s[st[j]], pbl[j] + k0);
        }
        __syncthreads();

        #pragma unroll
        for (int kh = 0; kh < 2; ++kh) {
            const int xo = kh * 32;
            bf16x8 Ah[4], Bh[8], Bl[8];
            #pragma unroll
            for (int i = 0; i < 4; ++i) Ah[i] = *(const bf16x8*)&Ah_s[oa[i] ^ xo];
            #pragma unroll
            for (int i = 0; i < 8; ++i) {
                Bh[i] = *(const bf16x8*)&Bh_s[ob[i] ^ xo];
                Bl[i] = *(const bf16x8*)&Bl_s[ob[i] ^ xo];
            }
            #pragma unroll
            for (int mi = 0; mi < 4; ++mi)
                #pragma unroll
                for (int ni = 0; ni < 8; ++ni) {
                    acc[mi][ni] = __builtin_amdgcn_mfma_f32_16x16x32_bf16(Ah[mi], Bh[ni], acc[mi][ni], 0, 0, 0);
                    acc[mi][ni] = __builtin_amdgcn_mfma_f32_16x16x32_bf16(Ah[mi], Bl[ni], acc[mi][ni], 0, 0, 0);
                }
        }
        __syncthreads();
    }

    #pragma unroll
    for (int mi = 0; mi < 4; ++mi) {
        int rbase = bm + wm * 64 + mi * 16 + quad * 4;
        #pragma unroll
        for (int r = 0; r < 4; ++r) {
            int grow = rbase + r;
            if (grow < M) {
                float s = dinv[grow];
                #pragma unroll
                for (int ni = 0; ni < 8; ++ni) {
                    int col = wn * 128 + ni * 16 + lm;
                    C[(size_t)grow * D + col] = (unsigned short)f2bf(acc[mi][ni][r] * s);
                }
            }
        }
    }
}

// ---------------- aggregation: out = relu(dinv*(h'[d] + sum h'[src]) + b) ----
// One node per wave; 2 edges per load instruction: lanes 0-31 gather edge j
// (ushort8 = 16B/lane, dims (lane&31)*8..+7), lanes 32-63 edge j+1. 8 loads
// in flight = 16 edges. Cross-half fold via __shfl_xor(32) at the end.

__global__ __launch_bounds__(256) void k_agg(
        const unsigned short* __restrict__ h, const float* __restrict__ dinv,
        const int* __restrict__ row_ptr, const int* __restrict__ col_src,
        const float* __restrict__ bias,
        unsigned short* __restrict__ ohi, int n) {
    int w = threadIdx.x >> 6, lane = threadIdx.x & 63;
    int node = blockIdx.x * 4 + w;
    if (node >= n) return;
    int half = lane >> 5;          // 0: even edges, 1: odd edges
    int dcol = lane & 31;          // owns dims dcol*8 .. dcol*8+7

    float acc[8] = {0.f, 0.f, 0.f, 0.f, 0.f, 0.f, 0.f, 0.f};
    if (half == 0) {               // self-loop on half 0 only
        u16x8 sv = ((const u16x8*)(h + (size_t)node * D))[dcol];
        #pragma unroll
        for (int d = 0; d < 8; ++d) acc[d] = bf2f((short)sv[d]);
    }

    int beg = row_ptr[node], end = row_ptr[node + 1];
    for (int c = beg; c < end; c += 64) {
        int cnt = min(64, end - c);                        // wave-uniform
        int myidx = (lane < cnt) ? col_src[c + lane] : 0;  // coalesced index load
        for (int e = 0; e < cnt; e += 16) {                // 8 instrs x 2 edges
            u16x8 u[8];
            bool val[8];
            #pragma unroll
            for (int j = 0; j < 8; ++j) {
                int eid = e + j * 2 + half;
                val[j] = eid < cnt;
                if (val[j]) {
                    int s = __shfl(myidx, eid);            // per-lane pull
                    u[j] = ((const u16x8*)(h + (size_t)s * D))[dcol];
                }
            }
            #pragma unroll
            for (int j = 0; j < 8; ++j)
                if (val[j]) {
                    #pragma unroll
                    for (int d = 0; d < 8; ++d) acc[d] += bf2f((short)u[j][d]);
                }
        }
    }

    // fold halves: lane L += lane L^32
    #pragma unroll
    for (int d = 0; d < 8; ++d) acc[d] += __shfl_xor(acc[d], 32);

    if (half == 0) {
        float di = dinv[node];
        float4 b0 = ((const float4*)bias)[dcol * 2];
        float4 b1 = ((const float4*)bias)[dcol * 2 + 1];
        float bb[8] = {b0.x, b0.y, b0.z, b0.w, b1.x, b1.y, b1.z, b1.w};
        u16x8 o;
        #pragma unroll
        for (int d = 0; d < 8; ++d)
            o[d] = (unsigned short)f2bf(fmaxf(acc[d] * di + bb[d], 0.f));
        ((u16x8*)(ohi + (size_t)node * D))[dcol] = o;
    }
}

// ---------------- mean pool: chunked sums + atomic flush -------------------

__global__ __launch_bounds__(256) void k_pool_sum(
        const unsigned short* __restrict__ hi,
        const int* __restrict__ batch, float* __restrict__ pooled, int n) {
    int beg = blockIdx.x * 64;
    if (beg >= n) return;
    int end = min(beg + 64, n);
    int t = threadIdx.x;  // dim t
    float acc = 0.f;
    int cur = batch[beg];
    for (int i = beg; i < end; ++i) {
        int g = batch[i];
        if (g != cur) {
            atomicAdd(&pooled[cur * D + t], acc);
            acc = 0.f;
            cur = g;
        }
        acc += bf2f(hi[(size_t)i * D + t]);
    }
    atomicAdd(&pooled[cur * D + t], acc);
}

// ---------------- final FC ----------------

__global__ void k_fc(const float* __restrict__ pooled, const float* __restrict__ inv_cnt,
                     const float* __restrict__ W, const float* __restrict__ b,
                     float* __restrict__ out) {
    int t = blockIdx.x * blockDim.x + threadIdx.x;
    if (t >= NG * DOUT) return;
    int g = t >> 4, o = t & 15;
    float acc = 0.f;
    for (int k = 0; k < D; ++k) acc += pooled[g * D + k] * W[k * DOUT + o];
    out[t] = acc * inv_cnt[g] + b[o];
}

// ---------------- launch ----------------

extern "C" void kernel_launch(void* const* d_in, const int* in_sizes, int n_in,
                              void* d_out, int out_size, void* d_ws, size_t ws_size,
                              hipStream_t stream) {
    const float* x    = (const float*)d_in[0];
    const int*   eidx = (const int*)d_in[1];
    const int*   batch= (const int*)d_in[2];
    const float* W1   = (const float*)d_in[3];
    const float* b1   = (const float*)d_in[4];
    const float* W2   = (const float*)d_in[5];
    const float* b2   = (const float*)d_in[6];
    const float* W3   = (const float*)d_in[7];
    const float* b3   = (const float*)d_in[8];
    const float* Wfc  = (const float*)d_in[9];
    const float* bfc  = (const float*)d_in[10];
    float* out = (float*)d_out;

    const int n = in_sizes[0] / D;      // 50000
    const int E = in_sizes[1] / 2;      // 400000

    // workspace layout (256B aligned slabs)
    char* p = (char*)d_ws;
    auto take = [&](size_t bytes) -> void* {
        void* q = (void*)p;
        p += (bytes + 255) & ~(size_t)255;
        return q;
    };
    int*   cnt     = (int*)take((size_t)n * 4);
    int*   row_ptr = (int*)take((size_t)(n + 1) * 4);
    int*   cursor  = (int*)take((size_t)n * 4);
    int*   col_src = (int*)take((size_t)E * 4);
    int*   bsums   = (int*)take(256 * 4);
    float* dinv    = (float*)take((size_t)n * 4);
    float* inv_cnt = (float*)take((size_t)NG * 4);
    short* w1hi    = (short*)take((size_t)D * D * 2);
    short* w1lo    = (short*)take((size_t)D * D * 2);
    short* w2hi    = (short*)take((size_t)D * D * 2);
    short* w2lo    = (short*)take((size_t)D * D * 2);
    short* w3hi    = (short*)take((size_t)D * D * 2);
    short* w3lo    = (short*)take((size_t)D * D * 2);
    unsigned short* hbuf = (unsigned short*)take((size_t)n * D * 2);  // bf16 h'
    unsigned short* ahi  = (unsigned short*)take((size_t)n * D * 2);  // bf16 A
    float* pooled  = (float*)take((size_t)NG * D * 4);

    int tb = 256;
    int gn = (n + tb - 1) / tb;
    int ge = (E + tb - 1) / tb;
    int nb = (n + 1023) / 1024;   // 49 scan blocks
    int total4 = n * D / 4;
    int xblocks = (total4 + 255) / 256;

    k_init<<<gn, tb, 0, stream>>>(cnt, pooled, batch, inv_cnt, n);
    k_split_count<<<xblocks + 3 * 256 + ge, tb, 0, stream>>>(
        x, ahi, total4, xblocks,
        W1, w1hi, w1lo, W2, w2hi, w2lo, W3, w3hi, w3lo,
        eidx, cnt, E);
    k_scan1<<<nb, 256, 0, stream>>>(cnt, row_ptr, bsums, dinv, n);
    k_scan3<<<gn, tb, 0, stream>>>(row_ptr, bsums, cursor, n, E, nb);
    k_fill<<<ge, tb, 0, stream>>>(eidx, cursor, col_src, E);

    int ggrid = (n + 127) / 128;
    int agrid = (n + 3) / 4;

    k_gemm_mfma<<<ggrid, 256, 0, stream>>>(ahi, w1hi, w1lo, dinv, hbuf, n);
    k_agg<<<agrid, 256, 0, stream>>>(hbuf, dinv, row_ptr, col_src, b1, ahi, n);

    k_gemm_mfma<<<ggrid, 256, 0, stream>>>(ahi, w2hi, w2lo, dinv, hbuf, n);
    k_agg<<<agrid, 256, 0, stream>>>(hbuf, dinv, row_ptr, col_src, b2, ahi, n);

    k_gemm_mfma<<<ggrid, 256, 0, stream>>>(ahi, w3hi, w3lo, dinv, hbuf, n);
    k_agg<<<agrid, 256, 0, stream>>>(hbuf, dinv, row_ptr, col_src, b3, ahi, n);

    k_pool_sum<<<(n + 63) / 64, 256, 0, stream>>>(ahi, batch, pooled, n);
    k_fc<<<4, 256, 0, stream>>>(pooled, inv_cnt, Wfc, bfc, out);
}

// Round 14
// 364.158 us; speedup vs baseline: 1.1582x; 1.0099x over previous
//
#include <hip/hip_runtime.h>

#define NN 50000
#define NE 400000
#define NG 64
#define D 256
#define DOUT 16

typedef __attribute__((ext_vector_type(8))) short bf16x8;
typedef __attribute__((ext_vector_type(8))) unsigned short u16x8;
typedef __attribute__((ext_vector_type(4))) float f32x4;

__device__ __forceinline__ short f2bf(float x) {
    union { float f; unsigned u; } v; v.f = x;
    unsigned r = v.u + 0x7fffu + ((v.u >> 16) & 1u);   // RNE
    return (short)(r >> 16);
}
__device__ __forceinline__ float bf2f(short h) {
    union { float f; unsigned u; } v;
    v.u = ((unsigned)(unsigned short)h) << 16;
    return v.f;
}

// async global->LDS 16B copy (dest = wave-uniform base + lane*16)
__device__ __forceinline__ void async_cp16(void* lds, const void* g) {
    __builtin_amdgcn_global_load_lds(
        (const __attribute__((address_space(1))) unsigned int*)g,
        (__attribute__((address_space(3))) unsigned int*)lds, 16, 0, 0);
}

// ---------------- init: zero cnt + zero pooled + per-graph inv counts ------

__global__ void k_init(int* __restrict__ cnt, float* __restrict__ pooled,
                       const int* __restrict__ batch, float* __restrict__ inv_cnt,
                       int n) {
    int i = blockIdx.x * 256 + threadIdx.x;
    if (i < n) cnt[i] = 0;
    if (i < NG * D) pooled[i] = 0.f;
    if (blockIdx.x == 0 && threadIdx.x < NG) {
        int g = threadIdx.x;
        int lo = 0, hi = n;
        while (lo < hi) { int mid = (lo + hi) >> 1; if (batch[mid] < g) lo = mid + 1; else hi = mid; }
        int start = lo;
        hi = n;
        while (lo < hi) { int mid = (lo + hi) >> 1; if (batch[mid] < g + 1) lo = mid + 1; else hi = mid; }
        inv_cnt[g] = 1.f / fmaxf((float)(lo - start), 1.f);
    }
}

// ---------------- fused: x->bf16 + 3x W^T hi/lo split + edge count ---------

__global__ void k_split_count(const float* __restrict__ x, unsigned short* __restrict__ ahi,
                              int total4, int xblocks,
                              const float* __restrict__ W1, short* __restrict__ w1hi, short* __restrict__ w1lo,
                              const float* __restrict__ W2, short* __restrict__ w2hi, short* __restrict__ w2lo,
                              const float* __restrict__ W3, short* __restrict__ w3hi, short* __restrict__ w3lo,
                              const int* __restrict__ eidx, int* __restrict__ cnt, int E) {
    int b = blockIdx.x;
    if (b < xblocks) {
        int i = b * 256 + threadIdx.x;
        if (i >= total4) return;
        float4 v = ((const float4*)x)[i];
        ushort4 h;
        h.x = (unsigned short)f2bf(v.x);
        h.y = (unsigned short)f2bf(v.y);
        h.z = (unsigned short)f2bf(v.z);
        h.w = (unsigned short)f2bf(v.w);
        ((ushort4*)ahi)[i] = h;
    } else if (b < xblocks + 3 * 256) {
        int wb = b - xblocks;
        int which = wb >> 8;               // 0..2
        int idx = (wb & 255) * 256 + threadIdx.x;   // idx = n*256 + k
        int nn = idx >> 8, k = idx & 255;
        const float* W = (which == 0) ? W1 : (which == 1) ? W2 : W3;
        short* Whi = (which == 0) ? w1hi : (which == 1) ? w2hi : w3hi;
        short* Wlo = (which == 0) ? w1lo : (which == 1) ? w2lo : w3lo;
        float xv = W[k * 256 + nn];
        short h = f2bf(xv);
        Whi[idx] = h;
        Wlo[idx] = f2bf(xv - bf2f(h));
    } else {
        int e = (b - xblocks - 3 * 256) * 256 + threadIdx.x;
        if (e < E) atomicAdd(&cnt[eidx[E + e]], 1);
    }
}

// exclusive scan of cnt[n] -> excl[n] (+ dinv from final counts), 1024 elems/block
__global__ void k_scan1(const int* __restrict__ cnt, int* __restrict__ excl,
                        int* __restrict__ bsums, float* __restrict__ dinv, int n) {
    __shared__ int sh[256];
    int tid = threadIdx.x;
    int base = blockIdx.x * 1024;
    int v[4]; int tsum = 0;
    for (int j = 0; j < 4; ++j) {
        int i = base + tid * 4 + j;
        v[j] = (i < n) ? cnt[i] : 0;
        if (i < n) dinv[i] = rsqrtf((float)(v[j] + 1));  // +1 self-loop
        tsum += v[j];
    }
    sh[tid] = tsum; __syncthreads();
    for (int d = 1; d < 256; d <<= 1) {
        int t = (tid >= d) ? sh[tid - d] : 0;
        __syncthreads();
        sh[tid] += t;
        __syncthreads();
    }
    int run = sh[tid] - tsum;  // exclusive offset within block
    for (int j = 0; j < 4; ++j) {
        int i = base + tid * 4 + j;
        if (i < n) excl[i] = run;
        run += v[j];
    }
    if (tid == 255) bsums[blockIdx.x] = sh[255];
}

// add bsums-prefix (computed in-wave per block) -> row_ptr, cursor
__global__ void k_scan3(int* __restrict__ row_ptr, const int* __restrict__ bsums,
                        int* __restrict__ cursor, int n, int E, int nb) {
    __shared__ int off_s;
    int chunk = (int)(blockIdx.x >> 2);   // block covers 256 idxs, 4 blocks per 1024-chunk
    if (threadIdx.x < 64) {
        int v = ((int)threadIdx.x < nb && (int)threadIdx.x < chunk) ? bsums[threadIdx.x] : 0;
        #pragma unroll
        for (int d = 1; d < 64; d <<= 1) v += __shfl_xor(v, d);
        if (threadIdx.x == 0) off_s = v;
    }
    __syncthreads();
    int off = off_s;
    int i = blockIdx.x * 256 + threadIdx.x;
    if (i < n) {
        int v = row_ptr[i] + off;
        row_ptr[i] = v;
        cursor[i] = v;
    }
    if (i == 0) row_ptr[n] = E;
}

// ---------------- GEMM body: 128x256 tile, BK=64, global_load_lds staging --
// A bf16 [M][256] (hi only); Wt hi/lo bf16 [256 n][256 k]. 4 waves of 64x128.
// LDS row = 64 shorts; slot (r, chunk c) holds k-chunk q = c ^ ((r>>1)&7),
// folded into global source address. Second k-half frag offset = first ^ 32.
// A*B ~= Ah*Bh + Ah*Bl.

__device__ __forceinline__ void gemm_body(
        const unsigned short* __restrict__ A,
        const short* __restrict__ Whi, const short* __restrict__ Wlo,
        const float* __restrict__ dinv, unsigned short* __restrict__ C, int M,
        int bm, short* Ah_s, short* Bh_s, short* Bl_s) {
    const int tid = threadIdx.x;
    const int lane = tid & 63;
    const int w    = tid >> 6;
    const int wm   = w & 1;        // wave row half (0-1): 64 rows
    const int wn   = w >> 1;       // wave col half (0-1): 128 cols
    const int lm   = lane & 15;
    const int quad = lane >> 4;

    const int srow = tid >> 3, c = tid & 7;
    const int q = c ^ ((srow >> 1) & 7);
    const unsigned short* pa[4];
    #pragma unroll
    for (int j = 0; j < 4; ++j) {
        int ga = bm + j * 32 + srow; if (ga >= M) ga = M - 1;
        pa[j] = A + ((size_t)ga << 8) + q * 8;
    }
    const short* pbh[8]; const short* pbl[8];
    #pragma unroll
    for (int j = 0; j < 8; ++j) {
        pbh[j] = Whi + ((size_t)(j * 32 + srow) << 8) + q * 8;
        pbl[j] = Wlo + ((size_t)(j * 32 + srow) << 8) + q * 8;
    }

    int st[8];
    #pragma unroll
    for (int j = 0; j < 8; ++j) st[j] = j * 2048 + w * 512;

    int oa[4], ob[8];
    #pragma unroll
    for (int i = 0; i < 4; ++i) {
        int ra = wm * 64 + i * 16 + lm;
        oa[i] = ra * 64 + ((quad ^ ((ra >> 1) & 7)) * 8);
    }
    #pragma unroll
    for (int i = 0; i < 8; ++i) {
        int rb = wn * 128 + i * 16 + lm;
        ob[i] = rb * 64 + ((quad ^ ((rb >> 1) & 7)) * 8);
    }

    f32x4 acc[4][8];
    #pragma unroll
    for (int i = 0; i < 4; ++i)
        #pragma unroll
        for (int j = 0; j < 8; ++j)
            acc[i][j] = (f32x4){0.f, 0.f, 0.f, 0.f};

    for (int k0 = 0; k0 < D; k0 += 64) {
        #pragma unroll
        for (int j = 0; j < 4; ++j) async_cp16(&Ah_s[st[j]], pa[j] + k0);
        #pragma unroll
        for (int j = 0; j < 8; ++j) {
            async_cp16(&Bh_s[st[j]], pbh[j] + k0);
            async_cp16(&Bl_s[st[j]], pbl[j] + k0);
        }
        __syncthreads();

        #pragma unroll
        for (int kh = 0; kh < 2; ++kh) {
            const int xo = kh * 32;
            bf16x8 Ah[4], Bh[8], Bl[8];
            #pragma unroll
            for (int i = 0; i < 4; ++i) Ah[i] = *(const bf16x8*)&Ah_s[oa[i] ^ xo];
            #pragma unroll
            for (int i = 0; i < 8; ++i) {
                Bh[i] = *(const bf16x8*)&Bh_s[ob[i] ^ xo];
                Bl[i] = *(const bf16x8*)&Bl_s[ob[i] ^ xo];
            }
            #pragma unroll
            for (int mi = 0; mi < 4; ++mi)
                #pragma unroll
                for (int ni = 0; ni < 8; ++ni) {
                    acc[mi][ni] = __builtin_amdgcn_mfma_f32_16x16x32_bf16(Ah[mi], Bh[ni], acc[mi][ni], 0, 0, 0);
                    acc[mi][ni] = __builtin_amdgcn_mfma_f32_16x16x32_bf16(Ah[mi], Bl[ni], acc[mi][ni], 0, 0, 0);
                }
        }
        __syncthreads();
    }

    #pragma unroll
    for (int mi = 0; mi < 4; ++mi) {
        int rbase = bm + wm * 64 + mi * 16 + quad * 4;
        #pragma unroll
        for (int r = 0; r < 4; ++r) {
            int grow = rbase + r;
            if (grow < M) {
                float s = dinv[grow];
                #pragma unroll
                for (int ni = 0; ni < 8; ++ni) {
                    int col = wn * 128 + ni * 16 + lm;
                    C[(size_t)grow * D + col] = (unsigned short)f2bf(acc[mi][ni][r] * s);
                }
            }
        }
    }
}

// layers 2-3: plain GEMM
__global__ __launch_bounds__(256, 2) void k_gemm_mfma(
        const unsigned short* __restrict__ A,
        const short* __restrict__ Whi, const short* __restrict__ Wlo,
        const float* __restrict__ dinv, unsigned short* __restrict__ C, int M) {
    __shared__ short Ah_s[8192];    // 16 KB
    __shared__ short Bh_s[16384];   // 32 KB
    __shared__ short Bl_s[16384];   // 32 KB
    gemm_body(A, Whi, Wlo, dinv, C, M, blockIdx.x * 128, Ah_s, Bh_s, Bl_s);
}

// layer 1: GEMM + CSR fill fused in one grid (independent work; fill hides
// inside the latency-bound gemm). Blocks [0,gblocks) gemm, rest fill.
__global__ __launch_bounds__(256, 2) void k_gemm1_fill(
        const unsigned short* __restrict__ A,
        const short* __restrict__ Whi, const short* __restrict__ Wlo,
        const float* __restrict__ dinv, unsigned short* __restrict__ C, int M,
        int gblocks, const int* __restrict__ eidx, int* __restrict__ cursor,
        int* __restrict__ col_src, int E) {
    __shared__ short Ah_s[8192];
    __shared__ short Bh_s[16384];
    __shared__ short Bl_s[16384];
    if ((int)blockIdx.x < gblocks) {
        gemm_body(A, Whi, Wlo, dinv, C, M, blockIdx.x * 128, Ah_s, Bh_s, Bl_s);
    } else {
        int e = ((int)blockIdx.x - gblocks) * 256 + threadIdx.x;
        if (e < E) {
            int d = eidx[E + e];
            int pos = atomicAdd(&cursor[d], 1);
            col_src[pos] = eidx[e];
        }
    }
}

// ---------------- aggregation: out = relu(dinv*(h'[d] + sum h'[src]) + b) ----
// One node per wave; 2 edges per load instruction: lanes 0-31 gather edge j
// (ushort8 = 16B/lane, dims (lane&31)*8..+7), lanes 32-63 edge j+1. 8 loads
// in flight = 16 edges. Cross-half fold via __shfl_xor(32) at the end.

__global__ __launch_bounds__(256) void k_agg(
        const unsigned short* __restrict__ h, const float* __restrict__ dinv,
        const int* __restrict__ row_ptr, const int* __restrict__ col_src,
        const float* __restrict__ bias,
        unsigned short* __restrict__ ohi, int n) {
    int w = threadIdx.x >> 6, lane = threadIdx.x & 63;
    int node = blockIdx.x * 4 + w;
    if (node >= n) return;
    int half = lane >> 5;          // 0: even edges, 1: odd edges
    int dcol = lane & 31;          // owns dims dcol*8 .. dcol*8+7

    float acc[8] = {0.f, 0.f, 0.f, 0.f, 0.f, 0.f, 0.f, 0.f};
    if (half == 0) {               // self-loop on half 0 only
        u16x8 sv = ((const u16x8*)(h + (size_t)node * D))[dcol];
        #pragma unroll
        for (int d = 0; d < 8; ++d) acc[d] = bf2f((short)sv[d]);
    }

    int beg = row_ptr[node], end = row_ptr[node + 1];
    for (int c = beg; c < end; c += 64) {
        int cnt = min(64, end - c);                        // wave-uniform
        int myidx = (lane < cnt) ? col_src[c + lane] : 0;  // coalesced index load
        for (int e = 0; e < cnt; e += 16) {                // 8 instrs x 2 edges
            u16x8 u[8];
            bool val[8];
            #pragma unroll
            for (int j = 0; j < 8; ++j) {
                int eid = e + j * 2 + half;
                val[j] = eid < cnt;
                if (val[j]) {
                    int s = __shfl(myidx, eid);            // per-lane pull
                    u[j] = ((const u16x8*)(h + (size_t)s * D))[dcol];
                }
            }
            #pragma unroll
            for (int j = 0; j < 8; ++j)
                if (val[j]) {
                    #pragma unroll
                    for (int d = 0; d < 8; ++d) acc[d] += bf2f((short)u[j][d]);
                }
        }
    }

    // fold halves: lane L += lane L^32
    #pragma unroll
    for (int d = 0; d < 8; ++d) acc[d] += __shfl_xor(acc[d], 32);

    if (half == 0) {
        float di = dinv[node];
        float4 b0 = ((const float4*)bias)[dcol * 2];
        float4 b1 = ((const float4*)bias)[dcol * 2 + 1];
        float bb[8] = {b0.x, b0.y, b0.z, b0.w, b1.x, b1.y, b1.z, b1.w};
        u16x8 o;
        #pragma unroll
        for (int d = 0; d < 8; ++d)
            o[d] = (unsigned short)f2bf(fmaxf(acc[d] * di + bb[d], 0.f));
        ((u16x8*)(ohi + (size_t)node * D))[dcol] = o;
    }
}

// ---------------- mean pool: chunked sums + atomic flush -------------------

__global__ __launch_bounds__(256) void k_pool_sum(
        const unsigned short* __restrict__ hi,
        const int* __restrict__ batch, float* __restrict__ pooled, int n) {
    int beg = blockIdx.x * 64;
    if (beg >= n) return;
    int end = min(beg + 64, n);
    int t = threadIdx.x;  // dim t
    float acc = 0.f;
    int cur = batch[beg];
    for (int i = beg; i < end; ++i) {
        int g = batch[i];
        if (g != cur) {
            atomicAdd(&pooled[cur * D + t], acc);
            acc = 0.f;
            cur = g;
        }
        acc += bf2f(hi[(size_t)i * D + t]);
    }
    atomicAdd(&pooled[cur * D + t], acc);
}

// ---------------- final FC ----------------

__global__ void k_fc(const float* __restrict__ pooled, const float* __restrict__ inv_cnt,
                     const float* __restrict__ W, const float* __restrict__ b,
                     float* __restrict__ out) {
    int t = blockIdx.x * blockDim.x + threadIdx.x;
    if (t >= NG * DOUT) return;
    int g = t >> 4, o = t & 15;
    float acc = 0.f;
    for (int k = 0; k < D; ++k) acc += pooled[g * D + k] * W[k * DOUT + o];
    out[t] = acc * inv_cnt[g] + b[o];
}

// ---------------- launch ----------------

extern "C" void kernel_launch(void* const* d_in, const int* in_sizes, int n_in,
                              void* d_out, int out_size, void* d_ws, size_t ws_size,
                              hipStream_t stream) {
    const float* x    = (const float*)d_in[0];
    const int*   eidx = (const int*)d_in[1];
    const int*   batch= (const int*)d_in[2];
    const float* W1   = (const float*)d_in[3];
    const float* b1   = (const float*)d_in[4];
    const float* W2   = (const float*)d_in[5];
    const float* b2   = (const float*)d_in[6];
    const float* W3   = (const float*)d_in[7];
    const float* b3   = (const float*)d_in[8];
    const float* Wfc  = (const float*)d_in[9];
    const float* bfc  = (const float*)d_in[10];
    float* out = (float*)d_out;

    const int n = in_sizes[0] / D;      // 50000
    const int E = in_sizes[1] / 2;      // 400000

    // workspace layout (256B aligned slabs)
    char* p = (char*)d_ws;
    auto take = [&](size_t bytes) -> void* {
        void* q = (void*)p;
        p += (bytes + 255) & ~(size_t)255;
        return q;
    };
    int*   cnt     = (int*)take((size_t)n * 4);
    int*   row_ptr = (int*)take((size_t)(n + 1) * 4);
    int*   cursor  = (int*)take((size_t)n * 4);
    int*   col_src = (int*)take((size_t)E * 4);
    int*   bsums   = (int*)take(256 * 4);
    float* dinv    = (float*)take((size_t)n * 4);
    float* inv_cnt = (float*)take((size_t)NG * 4);
    short* w1hi    = (short*)take((size_t)D * D * 2);
    short* w1lo    = (short*)take((size_t)D * D * 2);
    short* w2hi    = (short*)take((size_t)D * D * 2);
    short* w2lo    = (short*)take((size_t)D * D * 2);
    short* w3hi    = (short*)take((size_t)D * D * 2);
    short* w3lo    = (short*)take((size_t)D * D * 2);
    unsigned short* hbuf = (unsigned short*)take((size_t)n * D * 2);  // bf16 h'
    unsigned short* ahi  = (unsigned short*)take((size_t)n * D * 2);  // bf16 A
    float* pooled  = (float*)take((size_t)NG * D * 4);

    int tb = 256;
    int gn = (n + tb - 1) / tb;
    int ge = (E + tb - 1) / tb;
    int nb = (n + 1023) / 1024;   // 49 scan blocks
    int total4 = n * D / 4;
    int xblocks = (total4 + 255) / 256;

    k_init<<<gn, tb, 0, stream>>>(cnt, pooled, batch, inv_cnt, n);
    k_split_count<<<xblocks + 3 * 256 + ge, tb, 0, stream>>>(
        x, ahi, total4, xblocks,
        W1, w1hi, w1lo, W2, w2hi, w2lo, W3, w3hi, w3lo,
        eidx, cnt, E);
    k_scan1<<<nb, 256, 0, stream>>>(cnt, row_ptr, bsums, dinv, n);
    k_scan3<<<gn, tb, 0, stream>>>(row_ptr, bsums, cursor, n, E, nb);

    int ggrid = (n + 127) / 128;
    int agrid = (n + 3) / 4;

    // layer-1 GEMM fused with CSR fill (independent; fill hides inside gemm)
    k_gemm1_fill<<<ggrid + ge, 256, 0, stream>>>(ahi, w1hi, w1lo, dinv, hbuf, n,
                                                 ggrid, eidx, cursor, col_src, E);
    k_agg<<<agrid, 256, 0, stream>>>(hbuf, dinv, row_ptr, col_src, b1, ahi, n);

    k_gemm_mfma<<<ggrid, 256, 0, stream>>>(ahi, w2hi, w2lo, dinv, hbuf, n);
    k_agg<<<agrid, 256, 0, stream>>>(hbuf, dinv, row_ptr, col_src, b2, ahi, n);

    k_gemm_mfma<<<ggrid, 256, 0, stream>>>(ahi, w3hi, w3lo, dinv, hbuf, n);
    k_agg<<<agrid, 256, 0, stream>>>(hbuf, dinv, row_ptr, col_src, b3, ahi, n);

    k_pool_sum<<<(n + 63) / 64, 256, 0, stream>>>(ahi, batch, pooled, n);
    k_fc<<<4, 256, 0, stream>>>(pooled, inv_cnt, Wfc, bfc, out);
}